// Round 2
// 740.666 us; speedup vs baseline: 1.0255x; 1.0255x over previous
//
#include <hip/hip_runtime.h>
#include <hip/hip_bf16.h>

#define T_DIM 4096
#define D_DIM 1024
#define DFF   2048
#define E_NUM 8

typedef short short8 __attribute__((ext_vector_type(8)));
typedef float f32x4  __attribute__((ext_vector_type(4)));

__device__ __forceinline__ unsigned short f2bf(float f) {
  union { float f; unsigned u; } v; v.f = f;
  unsigned r = v.u + 0x7FFFu + ((v.u >> 16) & 1u);   // round-to-nearest-even
  return (unsigned short)(r >> 16);
}

__device__ __forceinline__ void load_lds16(const unsigned short* g, unsigned short* l) {
  __builtin_amdgcn_global_load_lds((const __attribute__((address_space(1))) void*)g,
                                   (__attribute__((address_space(3))) void*)l, 16, 0, 0);
}

// ---------------- probe: one wave per token, all 8 experts (x read once, not 8x).
// Same fp32 dot order + shfl reduction as the previously-passing version, so the
// mask boundary decision is bit-identical.
__global__ void probe_kernel(const float* __restrict__ x, const float* __restrict__ Wp,
                             const float* __restrict__ bp, const float* __restrict__ tb,
                             const float* __restrict__ gm, const float* __restrict__ wdp,
                             float* __restrict__ scale) {
  int wave = threadIdx.x >> 6;
  int lane = threadIdx.x & 63;
  int t = blockIdx.x * 4 + wave;
  const float4* xr = (const float4*)(x + (size_t)t * D_DIM);
  float4 a[4];
#pragma unroll
  for (int k = 0; k < 4; k++) a[k] = xr[k * 64 + lane];
  float z = wdp[0] * 0.5f;                                  // w_depth * depth_ratio
  float tau = tb[0] + gm[0] * (z / (1.f + expf(-z)));       // tau_base + gamma*silu(z)
#pragma unroll
  for (int e = 0; e < E_NUM; e++) {
    const float4* wr = (const float4*)(Wp + (size_t)e * D_DIM);
    float acc = 0.f;
#pragma unroll
    for (int k = 0; k < 4; k++) {
      float4 b = wr[k * 64 + lane];
      acc += a[k].x * b.x + a[k].y * b.y + a[k].z * b.z + a[k].w * b.w;
    }
#pragma unroll
    for (int off = 32; off > 0; off >>= 1) acc += __shfl_down(acc, off);
    if (lane == 0) {
      float logit = acc + bp[e];
      scale[t * E_NUM + e] = (logit > tau) ? (1.f / (1.f + expf(-logit))) : 0.f;
    }
  }
}

// ---------------- per-expert token compaction. Order-independent (sum over tokens
// commutes; down uses atomics anyway). idx/scs/count pre-zeroed by launcher, so pad
// slots have scs=0 (forces h=0) and idx=0 (in-bounds scatter of exact 0.0).
__global__ void compact_kernel(const float* __restrict__ scale, int* __restrict__ idxb,
                               float* __restrict__ scsb, int* __restrict__ cntb) {
  int e = blockIdx.x;
  for (int t = threadIdx.x; t < T_DIM; t += 256) {
    float s = scale[t * E_NUM + e];
    if (s > 0.f) {                       // sigmoid(finite) > 0; inactive is exact 0
      int slot = atomicAdd(&cntb[e], 1);
      idxb[e * T_DIM + slot] = t;
      scsb[e * T_DIM + slot] = s;
    }
  }
}

// ---------------- fp32 -> bf16 converters
__global__ void cvt_kernel(const float* __restrict__ src, unsigned short* __restrict__ dst) {
  int i = blockIdx.x * 256 + threadIdx.x;   // one float4 per thread
  float4 v = ((const float4*)src)[i];
  ushort4 o;
  o.x = f2bf(v.x); o.y = f2bf(v.y); o.z = f2bf(v.z); o.w = f2bf(v.w);
  ((ushort4*)dst)[i] = o;
}

// all-expert weight convert: 3 tensors x 16.78M elements, one dispatch
__global__ void cvt_w_kernel(const float* __restrict__ wu, const float* __restrict__ wg,
                             const float* __restrict__ wdn,
                             unsigned short* __restrict__ ou, unsigned short* __restrict__ og,
                             unsigned short* __restrict__ od) {
  int m = blockIdx.y;
  size_t i = (size_t)blockIdx.x * 256 + threadIdx.x;
  const float* s = (m == 0) ? wu : (m == 1) ? wg : wdn;
  unsigned short* d = (m == 0) ? ou : (m == 1) ? og : od;
  float4 v = ((const float4*)s)[i];
  ushort4 o;
  o.x = f2bf(v.x); o.y = f2bf(v.y); o.z = f2bf(v.z); o.w = f2bf(v.w);
  ((ushort4*)d)[i] = o;
}

// per-expert weight convert (fallback path, 3 x 4.19M elements)
__global__ void cvt3_kernel(const float* __restrict__ wu, const float* __restrict__ wg,
                            const float* __restrict__ wdn,
                            unsigned short* __restrict__ ou, unsigned short* __restrict__ og,
                            unsigned short* __restrict__ od) {
  int b = blockIdx.x;                 // 3 * 2048 blocks; 2048 per matrix
  int m = b >> 11;
  int i = (b & 2047) * 256 + threadIdx.x;
  const float* s = (m == 0) ? wu : (m == 1) ? wg : wdn;
  unsigned short* d = (m == 0) ? ou : (m == 1) ? og : od;
  float4 v = ((const float4*)s)[i];
  ushort4 o;
  o.x = f2bf(v.x); o.y = f2bf(v.y); o.z = f2bf(v.z); o.w = f2bf(v.w);
  ((ushort4*)d)[i] = o;
}

// ---------------- up+gate GEMM over COMPACTED active tokens of expert e.
// Rows (slots) map to tokens via idxb; blocks past count[e] exit immediately.
// A-row staging uses per-lane global addresses (legal: global_load_lds source is
// per-lane; only the LDS dest must be lane-linear).
__global__ void __launch_bounds__(256, 2)
upgate_kernel(const unsigned short* __restrict__ A,
              const unsigned short* __restrict__ Bu_base,
              const unsigned short* __restrict__ Bg_base,
              size_t wstride, size_t hstride,
              const int* __restrict__ idxb, const float* __restrict__ scsb,
              const int* __restrict__ cntb, int e_base,
              unsigned short* __restrict__ H_base) {
  const int e = e_base + blockIdx.z;
  const int rowA0 = blockIdx.x * 128;
  if (rowA0 >= cntb[e]) return;                          // inactive slot block
  __shared__ unsigned short smem[3 * 128 * 32];          // 24576 B staging
  unsigned short* sA = smem;
  unsigned short* sU = smem + 4096;
  unsigned short* sG = smem + 8192;
  const unsigned short* Bu = Bu_base + (size_t)blockIdx.z * wstride;
  const unsigned short* Bg = Bg_base + (size_t)blockIdx.z * wstride;
  unsigned short* H = H_base + (size_t)blockIdx.z * hstride;
  const int tid = threadIdx.x;
  const int wave = tid >> 6, lane = tid & 63;
  const int quad = lane >> 4, l15 = lane & 15;
  const int wm = (wave >> 1) * 64, wn = (wave & 1) * 64;
  const int rowB0 = blockIdx.y * 128;

  f32x4 accU[4][4], accG[4][4];
#pragma unroll
  for (int i = 0; i < 4; i++)
#pragma unroll
    for (int j = 0; j < 4; j++) {
      accU[i][j] = (f32x4){0.f, 0.f, 0.f, 0.f};
      accG[i][j] = (f32x4){0.f, 0.f, 0.f, 0.f};
    }

  const int j0 = tid, j1 = tid + 256;          // 512 x 16B chunks per 8KB tile
  const int ar0 = rowA0 + (j0 >> 2), ar1 = rowA0 + (j1 >> 2);
  const int br0 = rowB0 + (j0 >> 2), br1 = rowB0 + (j1 >> 2);
  const int c0 = (j0 & 3) * 8, c1 = (j1 & 3) * 8;
  const int ta0 = idxb[e * T_DIM + ar0];       // slot -> token (pads -> 0, h zeroed)
  const int ta1 = idxb[e * T_DIM + ar1];

  for (int k0 = 0; k0 < D_DIM; k0 += 32) {
    __syncthreads();
    load_lds16(A  + (size_t)ta0 * D_DIM + k0 + c0, sA + j0 * 8);
    load_lds16(A  + (size_t)ta1 * D_DIM + k0 + c1, sA + j1 * 8);
    load_lds16(Bu + (size_t)br0 * D_DIM + k0 + c0, sU + j0 * 8);
    load_lds16(Bu + (size_t)br1 * D_DIM + k0 + c1, sU + j1 * 8);
    load_lds16(Bg + (size_t)br0 * D_DIM + k0 + c0, sG + j0 * 8);
    load_lds16(Bg + (size_t)br1 * D_DIM + k0 + c1, sG + j1 * 8);
    __syncthreads();

    short8 af[4], bu[4], bg[4];
#pragma unroll
    for (int mt = 0; mt < 4; mt++)
      af[mt] = *(const short8*)(sA + (wm + mt * 16 + l15) * 32 + quad * 8);
#pragma unroll
    for (int nt = 0; nt < 4; nt++) {
      bu[nt] = *(const short8*)(sU + (wn + nt * 16 + l15) * 32 + quad * 8);
      bg[nt] = *(const short8*)(sG + (wn + nt * 16 + l15) * 32 + quad * 8);
    }
#pragma unroll
    for (int mt = 0; mt < 4; mt++)
#pragma unroll
      for (int nt = 0; nt < 4; nt++) {
        accU[mt][nt] = __builtin_amdgcn_mfma_f32_16x16x32_bf16(af[mt], bu[nt], accU[mt][nt], 0, 0, 0);
        accG[mt][nt] = __builtin_amdgcn_mfma_f32_16x16x32_bf16(af[mt], bg[nt], accG[mt][nt], 0, 0, 0);
      }
  }

  // epilogue: h' = scs[e,slot] * up * silu(gate)  (C/D: col=lane&15, row=quad*4+reg)
#pragma unroll
  for (int mt = 0; mt < 4; mt++) {
#pragma unroll
    for (int r = 0; r < 4; r++) {
      int row = rowA0 + wm + mt * 16 + quad * 4 + r;
      float s = scsb[e * T_DIM + row];
#pragma unroll
      for (int nt = 0; nt < 4; nt++) {
        int col = rowB0 + wn + nt * 16 + l15;
        float u = accU[mt][nt][r];
        float g = accG[mt][nt][r];
        float h = s * u * (g / (1.f + __expf(-g)));
        H[(size_t)row * DFF + col] = f2bf(h);
      }
    }
  }
}

// ---------------- down GEMM over compacted slots: out[token,d] += h_e @ Wd_e^T
// Scatter via fp32 atomicAdd through idxb (pads add exact 0.0 to out row 0).
__global__ void __launch_bounds__(256, 2)
down_kernel(const unsigned short* __restrict__ A_base,
            const unsigned short* __restrict__ B_base,
            size_t hstride, size_t wstride,
            const int* __restrict__ idxb, const int* __restrict__ cntb, int e_base,
            float* __restrict__ out) {
  const int e = e_base + blockIdx.z;
  const int rowA0 = blockIdx.x * 128;
  if (rowA0 >= cntb[e]) return;
  __shared__ unsigned short smem[2 * 128 * 32];   // 16384 B staging
  unsigned short* sA = smem;
  unsigned short* sB = smem + 4096;
  const unsigned short* A = A_base + (size_t)blockIdx.z * hstride;
  const unsigned short* B = B_base + (size_t)blockIdx.z * wstride;
  const int tid = threadIdx.x;
  const int wave = tid >> 6, lane = tid & 63;
  const int quad = lane >> 4, l15 = lane & 15;
  const int wm = (wave >> 1) * 64, wn = (wave & 1) * 64;
  const int rowB0 = blockIdx.y * 128;

  f32x4 acc[4][4];
#pragma unroll
  for (int i = 0; i < 4; i++)
#pragma unroll
    for (int j = 0; j < 4; j++) acc[i][j] = (f32x4){0.f, 0.f, 0.f, 0.f};

  const int j0 = tid, j1 = tid + 256;
  const int ar0 = rowA0 + (j0 >> 2), ar1 = rowA0 + (j1 >> 2);
  const int br0 = rowB0 + (j0 >> 2), br1 = rowB0 + (j1 >> 2);
  const int c0 = (j0 & 3) * 8, c1 = (j1 & 3) * 8;

  for (int k0 = 0; k0 < DFF; k0 += 32) {
    __syncthreads();
    load_lds16(A + (size_t)ar0 * DFF + k0 + c0, sA + j0 * 8);
    load_lds16(A + (size_t)ar1 * DFF + k0 + c1, sA + j1 * 8);
    load_lds16(B + (size_t)br0 * DFF + k0 + c0, sB + j0 * 8);
    load_lds16(B + (size_t)br1 * DFF + k0 + c1, sB + j1 * 8);
    __syncthreads();

    short8 af[4], bf[4];
#pragma unroll
    for (int mt = 0; mt < 4; mt++)
      af[mt] = *(const short8*)(sA + (wm + mt * 16 + l15) * 32 + quad * 8);
#pragma unroll
    for (int nt = 0; nt < 4; nt++)
      bf[nt] = *(const short8*)(sB + (wn + nt * 16 + l15) * 32 + quad * 8);
#pragma unroll
    for (int mt = 0; mt < 4; mt++)
#pragma unroll
      for (int nt = 0; nt < 4; nt++)
        acc[mt][nt] = __builtin_amdgcn_mfma_f32_16x16x32_bf16(af[mt], bf[nt], acc[mt][nt], 0, 0, 0);
  }

  // expert-combine epilogue: scatter to token rows (out zeroed by launcher)
#pragma unroll
  for (int mt = 0; mt < 4; mt++) {
#pragma unroll
    for (int r = 0; r < 4; r++) {
      int row = rowA0 + wm + mt * 16 + quad * 4 + r;
      int tok = idxb[e * T_DIM + row];
#pragma unroll
      for (int nt = 0; nt < 4; nt++) {
        int col = rowB0 + wn + nt * 16 + l15;
        atomicAdd(&out[(size_t)tok * D_DIM + col], acc[mt][nt][r]);
      }
    }
  }
}

extern "C" void kernel_launch(void* const* d_in, const int* in_sizes, int n_in,
                              void* d_out, int out_size, void* d_ws, size_t ws_size,
                              hipStream_t stream) {
  const float* x   = (const float*)d_in[0];
  const float* Wp  = (const float*)d_in[1];
  const float* bp  = (const float*)d_in[2];
  const float* Wu  = (const float*)d_in[3];
  const float* Wg  = (const float*)d_in[4];
  const float* Wd  = (const float*)d_in[5];
  const float* tb  = (const float*)d_in[6];
  const float* gm  = (const float*)d_in[7];
  const float* wdp = (const float*)d_in[8];
  float* out = (float*)d_out;

  const size_t WSZ = (size_t)DFF * D_DIM;          // elements per expert weight matrix
  const size_t HSZ = (size_t)T_DIM * DFF;          // elements per expert h

  char* ws = (char*)d_ws;
  float* scale       = (float*)ws;                              // 128 KB @ 0
  int*   idxb        = (int*)(ws + 131072);                     // 128 KB
  float* scsb        = (float*)(ws + 262144);                   // 128 KB
  int*   cntb        = (int*)(ws + 393216);                     // 4 KB reserved
  unsigned short* xb = (unsigned short*)(ws + 397312);          // 8 MB
  const size_t HEAD  = 397312;

  // zero idx+scs+count (pads must read idx=0, scs=0)
  hipMemsetAsync(ws + 131072, 0, 266240, stream);
  probe_kernel<<<T_DIM / 4, 256, 0, stream>>>(x, Wp, bp, tb, gm, wdp, scale);
  compact_kernel<<<E_NUM, 256, 0, stream>>>(scale, idxb, scsb, cntb);
  cvt_kernel<<<T_DIM * D_DIM / 1024, 256, 0, stream>>>(x, xb);
  hipMemsetAsync(out, 0, (size_t)T_DIM * D_DIM * sizeof(float), stream);

  const size_t FULL_REQ = HEAD + 8388608 + 3 * (WSZ * 2) * E_NUM + HSZ * 2 * E_NUM; // ~243.7 MB
  if (ws_size >= FULL_REQ) {
    // -------- fused path: all experts in one upgate + one down dispatch
    unsigned short* wub = xb + (size_t)T_DIM * D_DIM;           // 32 MB
    unsigned short* wgb = wub + WSZ * E_NUM;                    // 32 MB
    unsigned short* wdb = wgb + WSZ * E_NUM;                    // 32 MB
    unsigned short* hb  = wdb + WSZ * E_NUM;                    // 128 MB

    dim3 gc(WSZ * E_NUM / 1024, 3);
    cvt_w_kernel<<<gc, 256, 0, stream>>>(Wu, Wg, Wd, wub, wgb, wdb);

    dim3 g1(T_DIM / 128, DFF / 128, E_NUM);
    upgate_kernel<<<g1, 256, 0, stream>>>(xb, wub, wgb, WSZ, HSZ, idxb, scsb, cntb, 0, hb);
    dim3 g2(T_DIM / 128, D_DIM / 128, E_NUM);
    down_kernel<<<g2, 256, 0, stream>>>(hb, wdb, HSZ, WSZ, idxb, cntb, 0, out);
  } else {
    // -------- fallback (~37 MB): per-expert loop, strides 0
    unsigned short* wub = xb + (size_t)T_DIM * D_DIM;           // 4 MB
    unsigned short* wgb = wub + WSZ;                            // 4 MB
    unsigned short* wdb = wgb + WSZ;                            // 4 MB
    unsigned short* hb  = wdb + WSZ;                            // 16 MB

    for (int e = 0; e < E_NUM; e++) {
      cvt3_kernel<<<3 * (DFF * D_DIM / 1024), 256, 0, stream>>>(
          Wu + e * WSZ, Wg + e * WSZ, Wd + e * WSZ, wub, wgb, wdb);
      dim3 g1(T_DIM / 128, DFF / 128, 1);
      upgate_kernel<<<g1, 256, 0, stream>>>(xb, wub, wgb, 0, 0, idxb, scsb, cntb, e, hb);
      dim3 g2(T_DIM / 128, D_DIM / 128, 1);
      down_kernel<<<g2, 256, 0, stream>>>(hb, wdb, 0, 0, idxb, cntb, e, out);
    }
  }
}

// Round 3
// 639.503 us; speedup vs baseline: 1.1878x; 1.1582x over previous
//
#include <hip/hip_runtime.h>
#include <hip/hip_bf16.h>

#define T_DIM 4096
#define D_DIM 1024
#define DFF   2048
#define E_NUM 8

typedef short short8 __attribute__((ext_vector_type(8)));
typedef float f32x4  __attribute__((ext_vector_type(4)));

__device__ __forceinline__ unsigned short f2bf(float f) {
  union { float f; unsigned u; } v; v.f = f;
  unsigned r = v.u + 0x7FFFu + ((v.u >> 16) & 1u);   // round-to-nearest-even
  return (unsigned short)(r >> 16);
}

__device__ __forceinline__ void load_lds16(const unsigned short* g, unsigned short* l) {
  __builtin_amdgcn_global_load_lds((const __attribute__((address_space(1))) void*)g,
                                   (__attribute__((address_space(3))) void*)l, 16, 0, 0);
}

// ---------------- probe: one wave per token, all 8 experts (x read once).
// fp32 dot order + shfl reduction identical to the passing version (mask boundary).
__global__ void probe_kernel(const float* __restrict__ x, const float* __restrict__ Wp,
                             const float* __restrict__ bp, const float* __restrict__ tb,
                             const float* __restrict__ gm, const float* __restrict__ wdp,
                             float* __restrict__ scale) {
  int wave = threadIdx.x >> 6;
  int lane = threadIdx.x & 63;
  int t = blockIdx.x * 4 + wave;
  const float4* xr = (const float4*)(x + (size_t)t * D_DIM);
  float4 a[4];
#pragma unroll
  for (int k = 0; k < 4; k++) a[k] = xr[k * 64 + lane];
  float z = wdp[0] * 0.5f;                                  // w_depth * depth_ratio
  float tau = tb[0] + gm[0] * (z / (1.f + expf(-z)));       // tau_base + gamma*silu(z)
#pragma unroll
  for (int e = 0; e < E_NUM; e++) {
    const float4* wr = (const float4*)(Wp + (size_t)e * D_DIM);
    float acc = 0.f;
#pragma unroll
    for (int k = 0; k < 4; k++) {
      float4 b = wr[k * 64 + lane];
      acc += a[k].x * b.x + a[k].y * b.y + a[k].z * b.z + a[k].w * b.w;
    }
#pragma unroll
    for (int off = 32; off > 0; off >>= 1) acc += __shfl_down(acc, off);
    if (lane == 0) {
      float logit = acc + bp[e];
      scale[t * E_NUM + e] = (logit > tau) ? (1.f / (1.f + expf(-logit))) : 0.f;
    }
  }
}

// ---------------- per-expert token compaction + inverse map.
// idx/scs pre-zeroed (pads: idx=0, scs=0 -> h=0); slotOf pre-set to -1.
__global__ void compact_kernel(const float* __restrict__ scale, int* __restrict__ idxb,
                               float* __restrict__ scsb, int* __restrict__ cntb,
                               int* __restrict__ slotOfb) {
  int e = blockIdx.x;
  for (int t = threadIdx.x; t < T_DIM; t += 256) {
    float s = scale[t * E_NUM + e];
    if (s > 0.f) {                       // sigmoid(finite) > 0; inactive is exact 0
      int slot = atomicAdd(&cntb[e], 1);
      idxb[e * T_DIM + slot] = t;
      scsb[e * T_DIM + slot] = s;
      slotOfb[e * T_DIM + t] = slot;
    }
  }
}

// ---------------- fp32 -> bf16 converters
__global__ void cvt_kernel(const float* __restrict__ src, unsigned short* __restrict__ dst) {
  int i = blockIdx.x * 256 + threadIdx.x;   // one float4 per thread
  float4 v = ((const float4*)src)[i];
  ushort4 o;
  o.x = f2bf(v.x); o.y = f2bf(v.y); o.z = f2bf(v.z); o.w = f2bf(v.w);
  ((ushort4*)dst)[i] = o;
}

__global__ void cvt_w_kernel(const float* __restrict__ wu, const float* __restrict__ wg,
                             const float* __restrict__ wdn,
                             unsigned short* __restrict__ ou, unsigned short* __restrict__ og,
                             unsigned short* __restrict__ od) {
  int m = blockIdx.y;
  size_t i = (size_t)blockIdx.x * 256 + threadIdx.x;
  const float* s = (m == 0) ? wu : (m == 1) ? wg : wdn;
  unsigned short* d = (m == 0) ? ou : (m == 1) ? og : od;
  float4 v = ((const float4*)s)[i];
  ushort4 o;
  o.x = f2bf(v.x); o.y = f2bf(v.y); o.z = f2bf(v.z); o.w = f2bf(v.w);
  ((ushort4*)d)[i] = o;
}

__global__ void cvt3_kernel(const float* __restrict__ wu, const float* __restrict__ wg,
                            const float* __restrict__ wdn,
                            unsigned short* __restrict__ ou, unsigned short* __restrict__ og,
                            unsigned short* __restrict__ od) {
  int b = blockIdx.x;                 // 3 * 2048 blocks; 2048 per matrix
  int m = b >> 11;
  int i = (b & 2047) * 256 + threadIdx.x;
  const float* s = (m == 0) ? wu : (m == 1) ? wg : wdn;
  unsigned short* d = (m == 0) ? ou : (m == 1) ? og : od;
  float4 v = ((const float4*)s)[i];
  ushort4 o;
  o.x = f2bf(v.x); o.y = f2bf(v.y); o.z = f2bf(v.z); o.w = f2bf(v.w);
  ((ushort4*)d)[i] = o;
}

// ---------------- up+gate GEMM over compacted active tokens.
// Fused path: 1D grid 4096, expert-affine XCD decode (z = wid%8 -> all blocks of an
// expert land on one XCD under round-robin dispatch; x fastest within so 32
// consecutive same-XCD blocks share each 0.5MB weight tile in that XCD's L2).
// Fallback path (3D grid, gridDim.y==16): old decode.
__global__ void __launch_bounds__(256, 2)
upgate_kernel(const unsigned short* __restrict__ A,
              const unsigned short* __restrict__ Bu_base,
              const unsigned short* __restrict__ Bg_base,
              size_t wstride, size_t hstride,
              const int* __restrict__ idxb, const float* __restrict__ scsb,
              const int* __restrict__ cntb, int e_base,
              unsigned short* __restrict__ H_base) {
  int x, y, z;
  if (gridDim.y == 1) {                   // fused: expert-affine XCD swizzle
    int wid = blockIdx.x;
    z = wid & 7;
    int i = wid >> 3;
    x = i & 31;                           // fastest: weight-tile reuse in L2
    y = i >> 5;
  } else {                                // fallback per-expert launch
    x = blockIdx.x; y = blockIdx.y; z = blockIdx.z;
  }
  const int e = e_base + z;
  const int rowA0 = x * 128;
  if (rowA0 >= cntb[e]) return;                          // inactive slot block
  __shared__ unsigned short smem[3 * 128 * 32];          // 24576 B staging
  unsigned short* sA = smem;
  unsigned short* sU = smem + 4096;
  unsigned short* sG = smem + 8192;
  const unsigned short* Bu = Bu_base + (size_t)z * wstride;
  const unsigned short* Bg = Bg_base + (size_t)z * wstride;
  unsigned short* H = H_base + (size_t)z * hstride;
  const int tid = threadIdx.x;
  const int wave = tid >> 6, lane = tid & 63;
  const int quad = lane >> 4, l15 = lane & 15;
  const int wm = (wave >> 1) * 64, wn = (wave & 1) * 64;
  const int rowB0 = y * 128;

  f32x4 accU[4][4], accG[4][4];
#pragma unroll
  for (int i2 = 0; i2 < 4; i2++)
#pragma unroll
    for (int j = 0; j < 4; j++) {
      accU[i2][j] = (f32x4){0.f, 0.f, 0.f, 0.f};
      accG[i2][j] = (f32x4){0.f, 0.f, 0.f, 0.f};
    }

  const int j0 = tid, j1 = tid + 256;          // 512 x 16B chunks per 8KB tile
  const int ar0 = rowA0 + (j0 >> 2), ar1 = rowA0 + (j1 >> 2);
  const int br0 = rowB0 + (j0 >> 2), br1 = rowB0 + (j1 >> 2);
  const int c0 = (j0 & 3) * 8, c1 = (j1 & 3) * 8;
  const int ta0 = idxb[e * T_DIM + ar0];       // slot -> token (pads -> 0, scs=0)
  const int ta1 = idxb[e * T_DIM + ar1];

  for (int k0 = 0; k0 < D_DIM; k0 += 32) {
    __syncthreads();
    load_lds16(A  + (size_t)ta0 * D_DIM + k0 + c0, sA + j0 * 8);
    load_lds16(A  + (size_t)ta1 * D_DIM + k0 + c1, sA + j1 * 8);
    load_lds16(Bu + (size_t)br0 * D_DIM + k0 + c0, sU + j0 * 8);
    load_lds16(Bu + (size_t)br1 * D_DIM + k0 + c1, sU + j1 * 8);
    load_lds16(Bg + (size_t)br0 * D_DIM + k0 + c0, sG + j0 * 8);
    load_lds16(Bg + (size_t)br1 * D_DIM + k0 + c1, sG + j1 * 8);
    __syncthreads();

    short8 af[4], bu[4], bg[4];
#pragma unroll
    for (int mt = 0; mt < 4; mt++)
      af[mt] = *(const short8*)(sA + (wm + mt * 16 + l15) * 32 + quad * 8);
#pragma unroll
    for (int nt = 0; nt < 4; nt++) {
      bu[nt] = *(const short8*)(sU + (wn + nt * 16 + l15) * 32 + quad * 8);
      bg[nt] = *(const short8*)(sG + (wn + nt * 16 + l15) * 32 + quad * 8);
    }
#pragma unroll
    for (int mt = 0; mt < 4; mt++)
#pragma unroll
      for (int nt = 0; nt < 4; nt++) {
        accU[mt][nt] = __builtin_amdgcn_mfma_f32_16x16x32_bf16(af[mt], bu[nt], accU[mt][nt], 0, 0, 0);
        accG[mt][nt] = __builtin_amdgcn_mfma_f32_16x16x32_bf16(af[mt], bg[nt], accG[mt][nt], 0, 0, 0);
      }
  }

  // epilogue: h' = scs[e,slot] * up * silu(gate)  (C/D: col=lane&15, row=quad*4+reg)
#pragma unroll
  for (int mt = 0; mt < 4; mt++) {
#pragma unroll
    for (int r = 0; r < 4; r++) {
      int row = rowA0 + wm + mt * 16 + quad * 4 + r;
      float s = scsb[e * T_DIM + row];
#pragma unroll
      for (int nt = 0; nt < 4; nt++) {
        int col = rowB0 + wn + nt * 16 + l15;
        float u = accU[mt][nt][r];
        float g = accG[mt][nt][r];
        float h = s * u * (g / (1.f + __expf(-g)));
        H[(size_t)row * DFF + col] = f2bf(h);
      }
    }
  }
}

// ---------------- fused-path down: dense-output-stationary gather GEMM, NO atomics.
// Block = 64-token x 128-D tile; loops all 8 experts, gathering compacted h rows via
// slotOf (inactive -> zeroed row), fp32 register accumulation across experts, single
// plain store. Grid 512 (1D): xcd=w%8 owns an 8-x-tile token range (gathered h stays
// in that XCD's L2 across the y sweep).
__global__ void __launch_bounds__(256, 2)
down_dense_kernel(const unsigned short* __restrict__ hb,    // [E][slot][DFF]
                  const unsigned short* __restrict__ wdb,   // [E][D][DFF]
                  const int* __restrict__ slotOfb,          // [E][T], -1 = inactive
                  const unsigned short* __restrict__ zrow,  // DFF zeros
                  float* __restrict__ out) {
  const size_t HSZ = (size_t)T_DIM * DFF;
  const size_t WSZ = (size_t)D_DIM * DFF;
  int wid = blockIdx.x;                 // 512
  int xcd = wid & 7;
  int i = wid >> 3;                     // 0..63
  int y = i & 7;                        // D tile (fastest)
  int xloc = i >> 3;                    // 0..7
  int xt = xcd * 8 + xloc;              // token tile 0..63
  const int rowT0 = xt * 64, rowB0 = y * 128;

  __shared__ unsigned short smem[(64 + 128) * 32];   // sA 4KB + sB 8KB
  unsigned short* sA = smem;
  unsigned short* sB = smem + 64 * 32;

  const int tid = threadIdx.x;
  const int wave = tid >> 6, lane = tid & 63;
  const int quad = lane >> 4, l15 = lane & 15;
  const int wn = wave * 32;             // wave tile: 64 rows x 32 cols

  f32x4 acc[4][2];
#pragma unroll
  for (int m = 0; m < 4; m++)
#pragma unroll
    for (int n = 0; n < 2; n++) acc[m][n] = (f32x4){0.f, 0.f, 0.f, 0.f};

  const int arA = tid >> 2;                      // 0..63 (A: 1 chunk/thread)
  const int cA  = (tid & 3) * 8;
  const int j0 = tid, j1 = tid + 256;            // B: 2 chunks/thread (128 rows)
  const int brB0 = j0 >> 2, brB1 = j1 >> 2;      // 0..63, 64..127
  const int cB = (tid & 3) * 8;
  const int tA = rowT0 + arA;                    // dense token of my A row

  for (int e = 0; e < E_NUM; e++) {
    int s = slotOfb[e * T_DIM + tA];
    const unsigned short* aptr = (s >= 0) ? hb + (size_t)e * HSZ + (size_t)s * DFF : zrow;
    const unsigned short* Bp = wdb + (size_t)e * WSZ + (size_t)rowB0 * DFF;
    for (int k0 = 0; k0 < DFF; k0 += 32) {
      __syncthreads();
      load_lds16(aptr + k0 + cA, sA + tid * 8);
      load_lds16(Bp + (size_t)brB0 * DFF + k0 + cB, sB + j0 * 8);
      load_lds16(Bp + (size_t)brB1 * DFF + k0 + cB, sB + j1 * 8);
      __syncthreads();

      short8 af[4], bf[2];
#pragma unroll
      for (int mt = 0; mt < 4; mt++)
        af[mt] = *(const short8*)(sA + (mt * 16 + l15) * 32 + quad * 8);
#pragma unroll
      for (int nt = 0; nt < 2; nt++)
        bf[nt] = *(const short8*)(sB + (wn + nt * 16 + l15) * 32 + quad * 8);
#pragma unroll
      for (int mt = 0; mt < 4; mt++)
#pragma unroll
        for (int nt = 0; nt < 2; nt++)
          acc[mt][nt] = __builtin_amdgcn_mfma_f32_16x16x32_bf16(af[mt], bf[nt], acc[mt][nt], 0, 0, 0);
    }
  }

  // single plain store (each (row,col) owned by exactly one thread)
#pragma unroll
  for (int mt = 0; mt < 4; mt++) {
#pragma unroll
    for (int r = 0; r < 4; r++) {
      int row = rowT0 + mt * 16 + quad * 4 + r;
#pragma unroll
      for (int nt = 0; nt < 2; nt++) {
        int col = rowB0 + wn + nt * 16 + l15;
        out[(size_t)row * D_DIM + col] = acc[mt][nt][r];
      }
    }
  }
}

// ---------------- fallback down (atomic scatter) — unchanged, used only when ws small
__global__ void __launch_bounds__(256, 2)
down_kernel(const unsigned short* __restrict__ A_base,
            const unsigned short* __restrict__ B_base,
            size_t hstride, size_t wstride,
            const int* __restrict__ idxb, const int* __restrict__ cntb, int e_base,
            float* __restrict__ out) {
  const int e = e_base + blockIdx.z;
  const int rowA0 = blockIdx.x * 128;
  if (rowA0 >= cntb[e]) return;
  __shared__ unsigned short smem[2 * 128 * 32];
  unsigned short* sA = smem;
  unsigned short* sB = smem + 4096;
  const unsigned short* A = A_base + (size_t)blockIdx.z * hstride;
  const unsigned short* B = B_base + (size_t)blockIdx.z * wstride;
  const int tid = threadIdx.x;
  const int wave = tid >> 6, lane = tid & 63;
  const int quad = lane >> 4, l15 = lane & 15;
  const int wm = (wave >> 1) * 64, wn = (wave & 1) * 64;
  const int rowB0 = blockIdx.y * 128;

  f32x4 acc[4][4];
#pragma unroll
  for (int i = 0; i < 4; i++)
#pragma unroll
    for (int j = 0; j < 4; j++) acc[i][j] = (f32x4){0.f, 0.f, 0.f, 0.f};

  const int j0 = tid, j1 = tid + 256;
  const int ar0 = rowA0 + (j0 >> 2), ar1 = rowA0 + (j1 >> 2);
  const int br0 = rowB0 + (j0 >> 2), br1 = rowB0 + (j1 >> 2);
  const int c0 = (j0 & 3) * 8, c1 = (j1 & 3) * 8;

  for (int k0 = 0; k0 < DFF; k0 += 32) {
    __syncthreads();
    load_lds16(A + (size_t)ar0 * DFF + k0 + c0, sA + j0 * 8);
    load_lds16(A + (size_t)ar1 * DFF + k0 + c1, sA + j1 * 8);
    load_lds16(B + (size_t)br0 * DFF + k0 + c0, sB + j0 * 8);
    load_lds16(B + (size_t)br1 * DFF + k0 + c1, sB + j1 * 8);
    __syncthreads();

    short8 af[4], bf[4];
#pragma unroll
    for (int mt = 0; mt < 4; mt++)
      af[mt] = *(const short8*)(sA + (wm + mt * 16 + l15) * 32 + quad * 8);
#pragma unroll
    for (int nt = 0; nt < 4; nt++)
      bf[nt] = *(const short8*)(sB + (wn + nt * 16 + l15) * 32 + quad * 8);
#pragma unroll
    for (int mt = 0; mt < 4; mt++)
#pragma unroll
      for (int nt = 0; nt < 4; nt++)
        acc[mt][nt] = __builtin_amdgcn_mfma_f32_16x16x32_bf16(af[mt], bf[nt], acc[mt][nt], 0, 0, 0);
  }

#pragma unroll
  for (int mt = 0; mt < 4; mt++) {
#pragma unroll
    for (int r = 0; r < 4; r++) {
      int row = rowA0 + wm + mt * 16 + quad * 4 + r;
      int tok = idxb[e * T_DIM + row];
#pragma unroll
      for (int nt = 0; nt < 4; nt++) {
        int col = rowB0 + wn + nt * 16 + l15;
        atomicAdd(&out[(size_t)tok * D_DIM + col], acc[mt][nt][r]);
      }
    }
  }
}

extern "C" void kernel_launch(void* const* d_in, const int* in_sizes, int n_in,
                              void* d_out, int out_size, void* d_ws, size_t ws_size,
                              hipStream_t stream) {
  const float* x   = (const float*)d_in[0];
  const float* Wp  = (const float*)d_in[1];
  const float* bp  = (const float*)d_in[2];
  const float* Wu  = (const float*)d_in[3];
  const float* Wg  = (const float*)d_in[4];
  const float* Wd  = (const float*)d_in[5];
  const float* tb  = (const float*)d_in[6];
  const float* gm  = (const float*)d_in[7];
  const float* wdp = (const float*)d_in[8];
  float* out = (float*)d_out;

  const size_t WSZ = (size_t)DFF * D_DIM;          // elements per expert weight matrix
  const size_t HSZ = (size_t)T_DIM * DFF;          // elements per expert h

  char* ws = (char*)d_ws;
  float* scale         = (float*)ws;                            // 128 KB @ 0
  int*   idxb          = (int*)(ws + 131072);                   // 128 KB
  float* scsb          = (float*)(ws + 262144);                 // 128 KB
  int*   slotOfb       = (int*)(ws + 393216);                   // 128 KB
  int*   cntb          = (int*)(ws + 524288);                   // 4 KB
  unsigned short* zrow = (unsigned short*)(ws + 528384);        // 8 KB zeros
  unsigned short* xb   = (unsigned short*)(ws + 536576);        // 8 MB
  const size_t HEAD    = 536576;

  hipMemsetAsync(ws + 131072, 0, 262144, stream);       // idxb + scsb = 0
  hipMemsetAsync(ws + 393216, 0xFF, 131072, stream);    // slotOf = -1
  hipMemsetAsync(ws + 524288, 0, 12288, stream);        // cntb + zrow = 0
  probe_kernel<<<T_DIM / 4, 256, 0, stream>>>(x, Wp, bp, tb, gm, wdp, scale);
  compact_kernel<<<E_NUM, 256, 0, stream>>>(scale, idxb, scsb, cntb, slotOfb);
  cvt_kernel<<<T_DIM * D_DIM / 1024, 256, 0, stream>>>(x, xb);

  const size_t FULL_REQ = HEAD + 8388608 + 3 * (WSZ * 2) * E_NUM + HSZ * 2 * E_NUM; // ~243.8 MB
  if (ws_size >= FULL_REQ) {
    // -------- fused path
    unsigned short* wub = xb + (size_t)T_DIM * D_DIM;           // 32 MB
    unsigned short* wgb = wub + WSZ * E_NUM;                    // 32 MB
    unsigned short* wdb = wgb + WSZ * E_NUM;                    // 32 MB
    unsigned short* hb  = wdb + WSZ * E_NUM;                    // 128 MB

    dim3 gc(WSZ * E_NUM / 1024, 3);
    cvt_w_kernel<<<gc, 256, 0, stream>>>(Wu, Wg, Wd, wub, wgb, wdb);

    // expert-affine XCD-swizzled 1D grids
    upgate_kernel<<<dim3(4096, 1, 1), 256, 0, stream>>>(xb, wub, wgb, WSZ, HSZ,
                                                        idxb, scsb, cntb, 0, hb);
    down_dense_kernel<<<dim3(512, 1, 1), 256, 0, stream>>>(hb, wdb, slotOfb, zrow, out);
  } else {
    // -------- fallback (~37 MB): per-expert loop, atomic down, out pre-zeroed
    hipMemsetAsync(out, 0, (size_t)T_DIM * D_DIM * sizeof(float), stream);
    unsigned short* wub = xb + (size_t)T_DIM * D_DIM;           // 4 MB
    unsigned short* wgb = wub + WSZ;                            // 4 MB
    unsigned short* wdb = wgb + WSZ;                            // 4 MB
    unsigned short* hb  = wdb + WSZ;                            // 16 MB

    for (int e = 0; e < E_NUM; e++) {
      cvt3_kernel<<<3 * (DFF * D_DIM / 1024), 256, 0, stream>>>(
          Wu + e * WSZ, Wg + e * WSZ, Wd + e * WSZ, wub, wgb, wdb);
      dim3 g1(T_DIM / 128, DFF / 128, 1);
      upgate_kernel<<<g1, 256, 0, stream>>>(xb, wub, wgb, 0, 0, idxb, scsb, cntb, e, hb);
      dim3 g2(T_DIM / 128, D_DIM / 128, 1);
      down_kernel<<<g2, 256, 0, stream>>>(hb, wdb, 0, 0, idxb, cntb, e, out);
    }
  }
}

// Round 5
// 559.870 us; speedup vs baseline: 1.3567x; 1.1422x over previous
//
#include <hip/hip_runtime.h>
#include <hip/hip_bf16.h>

#define T_DIM 4096
#define D_DIM 1024
#define DFF   2048
#define E_NUM 8

typedef short short8 __attribute__((ext_vector_type(8)));
typedef float f32x4  __attribute__((ext_vector_type(4)));

__device__ __forceinline__ unsigned short f2bf(float f) {
  union { float f; unsigned u; } v; v.f = f;
  unsigned r = v.u + 0x7FFFu + ((v.u >> 16) & 1u);   // round-to-nearest-even
  return (unsigned short)(r >> 16);
}

__device__ __forceinline__ void load_lds16(const unsigned short* g, unsigned short* l) {
  __builtin_amdgcn_global_load_lds((const __attribute__((address_space(1))) void*)g,
                                   (__attribute__((address_space(3))) void*)l, 16, 0, 0);
}

// ---------------- probe: one wave per token, all 8 experts (x read once).
// fp32 dot order + shfl reduction identical to the passing version (mask boundary).
__global__ void probe_kernel(const float* __restrict__ x, const float* __restrict__ Wp,
                             const float* __restrict__ bp, const float* __restrict__ tb,
                             const float* __restrict__ gm, const float* __restrict__ wdp,
                             float* __restrict__ scale) {
  int wave = threadIdx.x >> 6;
  int lane = threadIdx.x & 63;
  int t = blockIdx.x * 4 + wave;
  const float4* xr = (const float4*)(x + (size_t)t * D_DIM);
  float4 a[4];
#pragma unroll
  for (int k = 0; k < 4; k++) a[k] = xr[k * 64 + lane];
  float z = wdp[0] * 0.5f;                                  // w_depth * depth_ratio
  float tau = tb[0] + gm[0] * (z / (1.f + expf(-z)));       // tau_base + gamma*silu(z)
#pragma unroll
  for (int e = 0; e < E_NUM; e++) {
    const float4* wr = (const float4*)(Wp + (size_t)e * D_DIM);
    float acc = 0.f;
#pragma unroll
    for (int k = 0; k < 4; k++) {
      float4 b = wr[k * 64 + lane];
      acc += a[k].x * b.x + a[k].y * b.y + a[k].z * b.z + a[k].w * b.w;
    }
#pragma unroll
    for (int off = 32; off > 0; off >>= 1) acc += __shfl_down(acc, off);
    if (lane == 0) {
      float logit = acc + bp[e];
      scale[t * E_NUM + e] = (logit > tau) ? (1.f / (1.f + expf(-logit))) : 0.f;
    }
  }
}

// ---------------- per-expert token compaction + inverse map.
// idx/scs pre-zeroed (pads: idx=0, scs=0 -> h=0); slotOf pre-set to -1.
__global__ void compact_kernel(const float* __restrict__ scale, int* __restrict__ idxb,
                               float* __restrict__ scsb, int* __restrict__ cntb,
                               int* __restrict__ slotOfb) {
  int e = blockIdx.x;
  for (int t = threadIdx.x; t < T_DIM; t += 256) {
    float s = scale[t * E_NUM + e];
    if (s > 0.f) {                       // sigmoid(finite) > 0; inactive is exact 0
      int slot = atomicAdd(&cntb[e], 1);
      idxb[e * T_DIM + slot] = t;
      scsb[e * T_DIM + slot] = s;
      slotOfb[e * T_DIM + t] = slot;
    }
  }
}

// ---------------- fp32 -> bf16 converters
__global__ void cvt_kernel(const float* __restrict__ src, unsigned short* __restrict__ dst) {
  int i = blockIdx.x * 256 + threadIdx.x;   // one float4 per thread
  float4 v = ((const float4*)src)[i];
  ushort4 o;
  o.x = f2bf(v.x); o.y = f2bf(v.y); o.z = f2bf(v.z); o.w = f2bf(v.w);
  ((ushort4*)dst)[i] = o;
}

__global__ void cvt_w_kernel(const float* __restrict__ wu, const float* __restrict__ wg,
                             const float* __restrict__ wdn,
                             unsigned short* __restrict__ ou, unsigned short* __restrict__ og,
                             unsigned short* __restrict__ od) {
  int m = blockIdx.y;
  size_t i = (size_t)blockIdx.x * 256 + threadIdx.x;
  const float* s = (m == 0) ? wu : (m == 1) ? wg : wdn;
  unsigned short* d = (m == 0) ? ou : (m == 1) ? og : od;
  float4 v = ((const float4*)s)[i];
  ushort4 o;
  o.x = f2bf(v.x); o.y = f2bf(v.y); o.z = f2bf(v.z); o.w = f2bf(v.w);
  ((ushort4*)d)[i] = o;
}

__global__ void cvt3_kernel(const float* __restrict__ wu, const float* __restrict__ wg,
                            const float* __restrict__ wdn,
                            unsigned short* __restrict__ ou, unsigned short* __restrict__ og,
                            unsigned short* __restrict__ od) {
  int b = blockIdx.x;                 // 3 * 2048 blocks; 2048 per matrix
  int m = b >> 11;
  int i = (b & 2047) * 256 + threadIdx.x;
  const float* s = (m == 0) ? wu : (m == 1) ? wg : wdn;
  unsigned short* d = (m == 0) ? ou : (m == 1) ? og : od;
  float4 v = ((const float4*)s)[i];
  ushort4 o;
  o.x = f2bf(v.x); o.y = f2bf(v.y); o.z = f2bf(v.z); o.w = f2bf(v.w);
  ((ushort4*)d)[i] = o;
}

// ---------------- up+gate GEMM over compacted active tokens.
// 2-phase pipeline, counted vmcnt. RACE FIX (R4 post-mortem): s_barrier does NOT
// wait on lgkmcnt, so ds_reads of buffer p must be explicitly drained
// (s_waitcnt lgkmcnt(0) + sched_barrier) BEFORE the closing barrier; otherwise the
// next iteration's global_load_lds DMA can overwrite buffer p under an in-flight read.
__global__ void __launch_bounds__(256, 2)
upgate_kernel(const unsigned short* __restrict__ A,
              const unsigned short* __restrict__ Bu_base,
              const unsigned short* __restrict__ Bg_base,
              size_t wstride, size_t hstride,
              const int* __restrict__ idxb, const float* __restrict__ scsb,
              const int* __restrict__ cntb, int e_base,
              unsigned short* __restrict__ H_base) {
  int x, y, z;
  if (gridDim.y == 1) {                   // fused: expert-affine XCD swizzle
    int wid = blockIdx.x;
    z = wid & 7;
    int i = wid >> 3;
    x = i & 31;                           // fastest: weight-tile reuse in L2
    y = i >> 5;
  } else {                                // fallback per-expert launch
    x = blockIdx.x; y = blockIdx.y; z = blockIdx.z;
  }
  const int e = e_base + z;
  const int rowA0 = x * 128;
  if (rowA0 >= cntb[e]) return;                          // inactive slot block (uniform)
  __shared__ unsigned short smem[2 * 3 * 4096];          // 49152 B double-buffered
  const unsigned short* Bu = Bu_base + (size_t)z * wstride;
  const unsigned short* Bg = Bg_base + (size_t)z * wstride;
  unsigned short* H = H_base + (size_t)z * hstride;
  const int tid = threadIdx.x;
  const int wave = tid >> 6, lane = tid & 63;
  const int quad = lane >> 4, l15 = lane & 15;
  const int wm = (wave >> 1) * 64, wn = (wave & 1) * 64;
  const int rowB0 = y * 128;

  f32x4 accU[4][4], accG[4][4];
#pragma unroll
  for (int i2 = 0; i2 < 4; i2++)
#pragma unroll
    for (int j = 0; j < 4; j++) {
      accU[i2][j] = (f32x4){0.f, 0.f, 0.f, 0.f};
      accG[i2][j] = (f32x4){0.f, 0.f, 0.f, 0.f};
    }

  const int j0 = tid, j1 = tid + 256;          // 512 x 16B chunks per 8KB tile
  const int ar0 = rowA0 + (j0 >> 2), ar1 = rowA0 + (j1 >> 2);
  const int br0 = rowB0 + (j0 >> 2), br1 = rowB0 + (j1 >> 2);
  const int c0 = (j0 & 3) * 8, c1 = (j1 & 3) * 8;
  const int ta0 = idxb[e * T_DIM + ar0];       // slot -> token (pads -> 0, scs=0)
  const int ta1 = idxb[e * T_DIM + ar1];

#define UG_STAGE(pp, kk) do {                                                  \
    unsigned short* _b = smem + ((pp) ? 12288 : 0);                            \
    load_lds16(A  + (size_t)ta0 * D_DIM + (kk) + c0, _b + j0 * 8);             \
    load_lds16(A  + (size_t)ta1 * D_DIM + (kk) + c1, _b + j1 * 8);             \
    load_lds16(Bu + (size_t)br0 * D_DIM + (kk) + c0, _b + 4096 + j0 * 8);      \
    load_lds16(Bu + (size_t)br1 * D_DIM + (kk) + c1, _b + 4096 + j1 * 8);      \
    load_lds16(Bg + (size_t)br0 * D_DIM + (kk) + c0, _b + 8192 + j0 * 8);      \
    load_lds16(Bg + (size_t)br1 * D_DIM + (kk) + c1, _b + 8192 + j1 * 8);      \
  } while (0)

  UG_STAGE(0, 0);                              // prologue: stage 0 in flight
  int p = 0;
  for (int ks = 0; ks < 32; ks++) {
    if (ks < 31) {
      UG_STAGE(p ^ 1, (ks + 1) * 32);          // issue next stage (6 loads)
      asm volatile("s_waitcnt vmcnt(6)" ::: "memory");   // current stage landed
    } else {
      asm volatile("s_waitcnt vmcnt(0)" ::: "memory");
    }
    __builtin_amdgcn_sched_barrier(0);
    __builtin_amdgcn_s_barrier();              // all waves' stage-p data visible
    __builtin_amdgcn_sched_barrier(0);

    unsigned short* sA = smem + (p ? 12288 : 0);
    unsigned short* sU = sA + 4096;
    unsigned short* sG = sA + 8192;
    short8 af[4], bu[4], bg[4];
#pragma unroll
    for (int mt = 0; mt < 4; mt++)
      af[mt] = *(const short8*)(sA + (wm + mt * 16 + l15) * 32 + quad * 8);
#pragma unroll
    for (int nt = 0; nt < 4; nt++) {
      bu[nt] = *(const short8*)(sU + (wn + nt * 16 + l15) * 32 + quad * 8);
      bg[nt] = *(const short8*)(sG + (wn + nt * 16 + l15) * 32 + quad * 8);
    }
#pragma unroll
    for (int mt = 0; mt < 4; mt++)
#pragma unroll
      for (int nt = 0; nt < 4; nt++) {
        accU[mt][nt] = __builtin_amdgcn_mfma_f32_16x16x32_bf16(af[mt], bu[nt], accU[mt][nt], 0, 0, 0);
        accG[mt][nt] = __builtin_amdgcn_mfma_f32_16x16x32_bf16(af[mt], bg[nt], accG[mt][nt], 0, 0, 0);
      }
    // drain LDS reads of buffer p before any wave can overwrite it next iteration
    asm volatile("s_waitcnt lgkmcnt(0)" ::: "memory");
    __builtin_amdgcn_sched_barrier(0);
    __builtin_amdgcn_s_barrier();              // buffer p free for overwrite
    __builtin_amdgcn_sched_barrier(0);
    p ^= 1;
  }
#undef UG_STAGE

  // epilogue: h' = scs[e,slot] * up * silu(gate)  (C/D: col=lane&15, row=quad*4+reg)
#pragma unroll
  for (int mt = 0; mt < 4; mt++) {
#pragma unroll
    for (int r = 0; r < 4; r++) {
      int row = rowA0 + wm + mt * 16 + quad * 4 + r;
      float s = scsb[e * T_DIM + row];
#pragma unroll
      for (int nt = 0; nt < 4; nt++) {
        int col = rowB0 + wn + nt * 16 + l15;
        float u = accU[mt][nt][r];
        float g = accG[mt][nt][r];
        float h = s * u * (g / (1.f + __expf(-g)));
        H[(size_t)row * DFF + col] = f2bf(h);
      }
    }
  }
}

// ---------------- fused-path down: dense-output-stationary gather GEMM, NO atomics,
// 2-phase pipelined (vmcnt(3)) with the same lgkmcnt(0) race fix.
__global__ void __launch_bounds__(256, 2)
down_dense_kernel(const unsigned short* __restrict__ hb,    // [E][slot][DFF]
                  const unsigned short* __restrict__ wdb,   // [E][D][DFF]
                  const int* __restrict__ slotOfb,          // [E][T], -1 = inactive
                  const unsigned short* __restrict__ zrow,  // DFF zeros
                  float* __restrict__ out) {
  const size_t HSZ = (size_t)T_DIM * DFF;
  const size_t WSZ = (size_t)D_DIM * DFF;
  int wid = blockIdx.x;                 // 512
  int xcd = wid & 7;
  int i = wid >> 3;                     // 0..63
  int y = i & 7;                        // D tile (fastest)
  int xloc = i >> 3;                    // 0..7
  int xt = xcd * 8 + xloc;              // token tile 0..63
  const int rowT0 = xt * 64, rowB0 = y * 128;

  __shared__ unsigned short smem[2 * 6144];   // 24576 B double-buffered (A 4KB + B 8KB)

  const int tid = threadIdx.x;
  const int wave = tid >> 6, lane = tid & 63;
  const int quad = lane >> 4, l15 = lane & 15;
  const int wn = wave * 32;             // wave tile: 64 rows x 32 cols

  f32x4 acc[4][2];
#pragma unroll
  for (int m = 0; m < 4; m++)
#pragma unroll
    for (int n = 0; n < 2; n++) acc[m][n] = (f32x4){0.f, 0.f, 0.f, 0.f};

  const int cA  = (tid & 3) * 8;
  const int j0 = tid, j1 = tid + 256;            // B: 2 chunks/thread (128 rows)
  const int brB0 = j0 >> 2, brB1 = j1 >> 2;      // 0..63, 64..127
  const int cB = (tid & 3) * 8;
  const int tA = rowT0 + (tid >> 2);             // dense token of my A row

#define DN_ROWPTR(ee) ({                                                        \
    int _s = slotOfb[(ee) * T_DIM + tA];                                        \
    (_s >= 0) ? hb + (size_t)(ee) * HSZ + (size_t)_s * DFF : zrow; })

#define DN_STAGE(pp, ap, bp_, kk) do {                                          \
    unsigned short* _b = smem + ((pp) ? 6144 : 0);                              \
    load_lds16((ap) + (kk) + cA, _b + tid * 8);                                 \
    load_lds16((bp_) + (size_t)brB0 * DFF + (kk) + cB, _b + 2048 + j0 * 8);     \
    load_lds16((bp_) + (size_t)brB1 * DFF + (kk) + cB, _b + 2048 + j1 * 8);     \
  } while (0)

  const unsigned short* aptr = DN_ROWPTR(0);
  const unsigned short* Bp = wdb + (size_t)rowB0 * DFF;
  DN_STAGE(0, aptr, Bp, 0);                      // prologue: stage (e=0,k=0)
  int p = 0;
  for (int e = 0; e < E_NUM; e++) {
    const unsigned short* aptrN = (e < 7) ? DN_ROWPTR(e + 1) : aptr;
    const unsigned short* BpN = wdb + (size_t)(e < 7 ? e + 1 : e) * WSZ + (size_t)rowB0 * DFF;
    for (int ks = 0; ks < 64; ks++) {
      bool last = (e == 7) && (ks == 63);
      if (!last) {
        if (ks < 63) DN_STAGE(p ^ 1, aptr, Bp, (ks + 1) * 32);
        else         DN_STAGE(p ^ 1, aptrN, BpN, 0);
        asm volatile("s_waitcnt vmcnt(3)" ::: "memory");
      } else {
        asm volatile("s_waitcnt vmcnt(0)" ::: "memory");
      }
      __builtin_amdgcn_sched_barrier(0);
      __builtin_amdgcn_s_barrier();
      __builtin_amdgcn_sched_barrier(0);

      unsigned short* sA = smem + (p ? 6144 : 0);
      unsigned short* sB = sA + 2048;
      short8 af[4], bf[2];
#pragma unroll
      for (int mt = 0; mt < 4; mt++)
        af[mt] = *(const short8*)(sA + (mt * 16 + l15) * 32 + quad * 8);
#pragma unroll
      for (int nt = 0; nt < 2; nt++)
        bf[nt] = *(const short8*)(sB + (wn + nt * 16 + l15) * 32 + quad * 8);
#pragma unroll
      for (int mt = 0; mt < 4; mt++)
#pragma unroll
        for (int nt = 0; nt < 2; nt++)
          acc[mt][nt] = __builtin_amdgcn_mfma_f32_16x16x32_bf16(af[mt], bf[nt], acc[mt][nt], 0, 0, 0);
      // drain LDS reads of buffer p before it can be overwritten next iteration
      asm volatile("s_waitcnt lgkmcnt(0)" ::: "memory");
      __builtin_amdgcn_sched_barrier(0);
      __builtin_amdgcn_s_barrier();
      __builtin_amdgcn_sched_barrier(0);
      p ^= 1;
    }
    aptr = aptrN;
    Bp = BpN;
  }
#undef DN_STAGE
#undef DN_ROWPTR

  // single plain store (each (row,col) owned by exactly one thread)
#pragma unroll
  for (int mt = 0; mt < 4; mt++) {
#pragma unroll
    for (int r = 0; r < 4; r++) {
      int row = rowT0 + mt * 16 + quad * 4 + r;
#pragma unroll
      for (int nt = 0; nt < 2; nt++) {
        int col = rowB0 + wn + nt * 16 + l15;
        out[(size_t)row * D_DIM + col] = acc[mt][nt][r];
      }
    }
  }
}

// ---------------- fallback down (atomic scatter) — used only when ws small
__global__ void __launch_bounds__(256, 2)
down_kernel(const unsigned short* __restrict__ A_base,
            const unsigned short* __restrict__ B_base,
            size_t hstride, size_t wstride,
            const int* __restrict__ idxb, const int* __restrict__ cntb, int e_base,
            float* __restrict__ out) {
  const int e = e_base + blockIdx.z;
  const int rowA0 = blockIdx.x * 128;
  if (rowA0 >= cntb[e]) return;
  __shared__ unsigned short smem[2 * 128 * 32];
  unsigned short* sA = smem;
  unsigned short* sB = smem + 4096;
  const unsigned short* A = A_base + (size_t)blockIdx.z * hstride;
  const unsigned short* B = B_base + (size_t)blockIdx.z * wstride;
  const int tid = threadIdx.x;
  const int wave = tid >> 6, lane = tid & 63;
  const int quad = lane >> 4, l15 = lane & 15;
  const int wm = (wave >> 1) * 64, wn = (wave & 1) * 64;
  const int rowB0 = blockIdx.y * 128;

  f32x4 acc[4][4];
#pragma unroll
  for (int i = 0; i < 4; i++)
#pragma unroll
    for (int j = 0; j < 4; j++) acc[i][j] = (f32x4){0.f, 0.f, 0.f, 0.f};

  const int j0 = tid, j1 = tid + 256;
  const int ar0 = rowA0 + (j0 >> 2), ar1 = rowA0 + (j1 >> 2);
  const int br0 = rowB0 + (j0 >> 2), br1 = rowB0 + (j1 >> 2);
  const int c0 = (j0 & 3) * 8, c1 = (j1 & 3) * 8;

  for (int k0 = 0; k0 < DFF; k0 += 32) {
    __syncthreads();
    load_lds16(A + (size_t)ar0 * DFF + k0 + c0, sA + j0 * 8);
    load_lds16(A + (size_t)ar1 * DFF + k0 + c1, sA + j1 * 8);
    load_lds16(B + (size_t)br0 * DFF + k0 + c0, sB + j0 * 8);
    load_lds16(B + (size_t)br1 * DFF + k0 + c1, sB + j1 * 8);
    __syncthreads();

    short8 af[4], bf[4];
#pragma unroll
    for (int mt = 0; mt < 4; mt++)
      af[mt] = *(const short8*)(sA + (wm + mt * 16 + l15) * 32 + quad * 8);
#pragma unroll
    for (int nt = 0; nt < 4; nt++)
      bf[nt] = *(const short8*)(sB + (wn + nt * 16 + l15) * 32 + quad * 8);
#pragma unroll
    for (int mt = 0; mt < 4; mt++)
#pragma unroll
      for (int nt = 0; nt < 4; nt++)
        acc[mt][nt] = __builtin_amdgcn_mfma_f32_16x16x32_bf16(af[mt], bf[nt], acc[mt][nt], 0, 0, 0);
  }

#pragma unroll
  for (int mt = 0; mt < 4; mt++) {
#pragma unroll
    for (int r = 0; r < 4; r++) {
      int row = rowA0 + wm + mt * 16 + quad * 4 + r;
      int tok = idxb[e * T_DIM + row];
#pragma unroll
      for (int nt = 0; nt < 4; nt++) {
        int col = rowB0 + wn + nt * 16 + l15;
        atomicAdd(&out[(size_t)tok * D_DIM + col], acc[mt][nt][r]);
      }
    }
  }
}

extern "C" void kernel_launch(void* const* d_in, const int* in_sizes, int n_in,
                              void* d_out, int out_size, void* d_ws, size_t ws_size,
                              hipStream_t stream) {
  const float* x   = (const float*)d_in[0];
  const float* Wp  = (const float*)d_in[1];
  const float* bp  = (const float*)d_in[2];
  const float* Wu  = (const float*)d_in[3];
  const float* Wg  = (const float*)d_in[4];
  const float* Wd  = (const float*)d_in[5];
  const float* tb  = (const float*)d_in[6];
  const float* gm  = (const float*)d_in[7];
  const float* wdp = (const float*)d_in[8];
  float* out = (float*)d_out;

  const size_t WSZ = (size_t)DFF * D_DIM;          // elements per expert weight matrix
  const size_t HSZ = (size_t)T_DIM * DFF;          // elements per expert h

  char* ws = (char*)d_ws;
  float* scale         = (float*)ws;                            // 128 KB @ 0
  int*   idxb          = (int*)(ws + 131072);                   // 128 KB
  float* scsb          = (float*)(ws + 262144);                 // 128 KB
  int*   slotOfb       = (int*)(ws + 393216);                   // 128 KB
  int*   cntb          = (int*)(ws + 524288);                   // 4 KB
  unsigned short* zrow = (unsigned short*)(ws + 528384);        // 8 KB zeros
  unsigned short* xb   = (unsigned short*)(ws + 536576);        // 8 MB
  const size_t HEAD    = 536576;

  hipMemsetAsync(ws + 131072, 0, 262144, stream);       // idxb + scsb = 0
  hipMemsetAsync(ws + 393216, 0xFF, 131072, stream);    // slotOf = -1
  hipMemsetAsync(ws + 524288, 0, 12288, stream);        // cntb + zrow = 0
  probe_kernel<<<T_DIM / 4, 256, 0, stream>>>(x, Wp, bp, tb, gm, wdp, scale);
  compact_kernel<<<E_NUM, 256, 0, stream>>>(scale, idxb, scsb, cntb, slotOfb);
  cvt_kernel<<<T_DIM * D_DIM / 1024, 256, 0, stream>>>(x, xb);

  const size_t FULL_REQ = HEAD + 8388608 + 3 * (WSZ * 2) * E_NUM + HSZ * 2 * E_NUM; // ~243.8 MB
  if (ws_size >= FULL_REQ) {
    // -------- fused path
    unsigned short* wub = xb + (size_t)T_DIM * D_DIM;           // 32 MB
    unsigned short* wgb = wub + WSZ * E_NUM;                    // 32 MB
    unsigned short* wdb = wgb + WSZ * E_NUM;                    // 32 MB
    unsigned short* hb  = wdb + WSZ * E_NUM;                    // 128 MB

    dim3 gc(WSZ * E_NUM / 1024, 3);
    cvt_w_kernel<<<gc, 256, 0, stream>>>(Wu, Wg, Wd, wub, wgb, wdb);

    // expert-affine XCD-swizzled 1D grids
    upgate_kernel<<<dim3(4096, 1, 1), 256, 0, stream>>>(xb, wub, wgb, WSZ, HSZ,
                                                        idxb, scsb, cntb, 0, hb);
    down_dense_kernel<<<dim3(512, 1, 1), 256, 0, stream>>>(hb, wdb, slotOfb, zrow, out);
  } else {
    // -------- fallback (~37 MB): per-expert loop, atomic down, out pre-zeroed
    hipMemsetAsync(out, 0, (size_t)T_DIM * D_DIM * sizeof(float), stream);
    unsigned short* wub = xb + (size_t)T_DIM * D_DIM;           // 4 MB
    unsigned short* wgb = wub + WSZ;                            // 4 MB
    unsigned short* wdb = wgb + WSZ;                            // 4 MB
    unsigned short* hb  = wdb + WSZ;                            // 16 MB

    for (int e = 0; e < E_NUM; e++) {
      cvt3_kernel<<<3 * (DFF * D_DIM / 1024), 256, 0, stream>>>(
          Wu + e * WSZ, Wg + e * WSZ, Wd + e * WSZ, wub, wgb, wdb);
      dim3 g1(T_DIM / 128, DFF / 128, 1);
      upgate_kernel<<<g1, 256, 0, stream>>>(xb, wub, wgb, 0, 0, idxb, scsb, cntb, e, hb);
      dim3 g2(T_DIM / 128, D_DIM / 128, 1);
      down_kernel<<<g2, 256, 0, stream>>>(hb, wdb, 0, 0, idxb, cntb, e, out);
    }
  }
}